// Round 1
// baseline (501.324 us; speedup 1.0000x reference)
//
#include <hip/hip_runtime.h>

// Problem constants (B=1)
#define S_LEN 4096
#define E_DIM 1024
#define NH 8
#define DKD 128

typedef __attribute__((ext_vector_type(8))) short short8;
typedef __attribute__((ext_vector_type(4))) float f32x4;

__device__ __forceinline__ unsigned short f32_to_bf16(float f) {
  union { float f; unsigned u; } v; v.f = f;
  unsigned r = v.u + 0x7FFFu + ((v.u >> 16) & 1u);   // RNE
  return (unsigned short)(r >> 16);
}

// ---------------- fp32 -> bf16 conversion (4 elems/thread) ----------------
__global__ __launch_bounds__(256) void cvt_f32_bf16(const float* __restrict__ src,
                                                    unsigned short* __restrict__ dst,
                                                    int n) {
  int i = (blockIdx.x * 256 + threadIdx.x) * 4;
  if (i >= n) return;
  f32x4 v = *(const f32x4*)(src + i);
  uint2 pk;
  pk.x = (unsigned)f32_to_bf16(v.x) | ((unsigned)f32_to_bf16(v.y) << 16);
  pk.y = (unsigned)f32_to_bf16(v.z) | ((unsigned)f32_to_bf16(v.w) << 16);
  *(uint2*)(dst + i) = pk;
}

// ---------------- 128x128 bf16 GEMM core: C = A[M,K] * B[N,K]^T ----------------
// 256 threads = 4 waves in 2x2; each wave: 4x4 grid of 16x16 MFMA tiles.
// LDS rows padded to 40 elems (80 B): frag ds_read_b128 is 2-way conflict = free.
__device__ __forceinline__ void gemm128_core(const unsigned short* __restrict__ A,
                                             const unsigned short* __restrict__ B,
                                             int row0, int col0, int K,
                                             unsigned short* As, unsigned short* Bs,
                                             f32x4 acc[4][4]) {
  const int tid = threadIdx.x;
  const int lane = tid & 63;
  const int wave = tid >> 6;
  const int quad = lane >> 4;
  const int l15 = lane & 15;
  const int wm = (wave >> 1) * 64;
  const int wn = (wave & 1) * 64;
  const int r0 = tid >> 2;     // staging row 0..63 (second pass +64)
  const int c0 = tid & 3;      // 16B chunk within 32-elem row
  for (int k0 = 0; k0 < K; k0 += 32) {
    __syncthreads();
#pragma unroll
    for (int i = 0; i < 2; ++i) {
      int r = r0 + i * 64;
      *(f32x4*)(As + r * 40 + c0 * 8) =
          *(const f32x4*)(A + (size_t)(row0 + r) * K + k0 + c0 * 8);
      *(f32x4*)(Bs + r * 40 + c0 * 8) =
          *(const f32x4*)(B + (size_t)(col0 + r) * K + k0 + c0 * 8);
    }
    __syncthreads();
    short8 a[4], b[4];
#pragma unroll
    for (int mt = 0; mt < 4; ++mt)
      a[mt] = *(const short8*)(As + (wm + mt * 16 + l15) * 40 + quad * 8);
#pragma unroll
    for (int nt = 0; nt < 4; ++nt)
      b[nt] = *(const short8*)(Bs + (wn + nt * 16 + l15) * 40 + quad * 8);
#pragma unroll
    for (int mt = 0; mt < 4; ++mt)
#pragma unroll
      for (int nt = 0; nt < 4; ++nt)
        acc[mt][nt] = __builtin_amdgcn_mfma_f32_16x16x32_bf16(a[mt], b[nt], acc[mt][nt], 0, 0, 0);
  }
}

// ---------------- QKV projection: z=0/1/2 -> Q/K/V ----------------
__global__ __launch_bounds__(256) void proj_qkv(
    const unsigned short* __restrict__ qb, const unsigned short* __restrict__ kb,
    const unsigned short* __restrict__ vb, const unsigned short* __restrict__ Wb,
    const float* __restrict__ bq, const float* __restrict__ bk, const float* __restrict__ bv,
    unsigned short* __restrict__ Qh, unsigned short* __restrict__ Kh,
    unsigned short* __restrict__ Vh, float qscale) {
  __shared__ __attribute__((aligned(16))) unsigned short As[128 * 40];
  __shared__ __attribute__((aligned(16))) unsigned short Bs[128 * 40];
  const int z = blockIdx.z;
  const unsigned short* A = (z == 0) ? qb : (z == 1) ? kb : vb;
  const unsigned short* B = Wb + (size_t)z * E_DIM * E_DIM;
  const float* bias = (z == 0) ? bq : (z == 1) ? bk : bv;
  unsigned short* Out = (z == 0) ? Qh : (z == 1) ? Kh : Vh;
  const float scale = (z == 0) ? qscale : 1.0f;
  const int row0 = blockIdx.y * 128, col0 = blockIdx.x * 128;
  const f32x4 zero4 = {0.f, 0.f, 0.f, 0.f};
  f32x4 acc[4][4];
#pragma unroll
  for (int i = 0; i < 4; ++i)
#pragma unroll
    for (int j = 0; j < 4; ++j) acc[i][j] = zero4;
  gemm128_core(A, B, row0, col0, E_DIM, As, Bs, acc);
  const int lane = threadIdx.x & 63, wave = threadIdx.x >> 6;
  const int quad = lane >> 4, l15 = lane & 15;
  const int wm = (wave >> 1) * 64, wn = (wave & 1) * 64;
#pragma unroll
  for (int mt = 0; mt < 4; ++mt)
#pragma unroll
    for (int nt = 0; nt < 4; ++nt) {
      int gc = col0 + wn + nt * 16 + l15;
      float bv_ = bias[gc];
#pragma unroll
      for (int r = 0; r < 4; ++r) {
        int gr = row0 + wm + mt * 16 + quad * 4 + r;
        Out[(size_t)gr * E_DIM + gc] = f32_to_bf16((acc[mt][nt][r] + bv_) * scale);
      }
    }
}

// ---------------- output projection + bias + residual (fp32 out) ----------------
__global__ __launch_bounds__(256) void out_proj(
    const unsigned short* __restrict__ Zb, const unsigned short* __restrict__ Wob,
    const float* __restrict__ bo, const float* __restrict__ resid,
    float* __restrict__ Y) {
  __shared__ __attribute__((aligned(16))) unsigned short As[128 * 40];
  __shared__ __attribute__((aligned(16))) unsigned short Bs[128 * 40];
  const int row0 = blockIdx.y * 128, col0 = blockIdx.x * 128;
  const f32x4 zero4 = {0.f, 0.f, 0.f, 0.f};
  f32x4 acc[4][4];
#pragma unroll
  for (int i = 0; i < 4; ++i)
#pragma unroll
    for (int j = 0; j < 4; ++j) acc[i][j] = zero4;
  gemm128_core(Zb, Wob, row0, col0, E_DIM, As, Bs, acc);
  const int lane = threadIdx.x & 63, wave = threadIdx.x >> 6;
  const int quad = lane >> 4, l15 = lane & 15;
  const int wm = (wave >> 1) * 64, wn = (wave & 1) * 64;
#pragma unroll
  for (int mt = 0; mt < 4; ++mt)
#pragma unroll
    for (int nt = 0; nt < 4; ++nt) {
      int gc = col0 + wn + nt * 16 + l15;
      float bv_ = bo[gc];
#pragma unroll
      for (int r = 0; r < 4; ++r) {
        int gr = row0 + wm + mt * 16 + quad * 4 + r;
        Y[(size_t)gr * E_DIM + gc] = acc[mt][nt][r] + bv_ + resid[(size_t)gr * E_DIM + gc];
      }
    }
}

// ---------------- V transpose: Vh[S, H*DK] -> Vt[H][DK][S] ----------------
__global__ __launch_bounds__(256) void transpose_v(const unsigned short* __restrict__ Vh,
                                                   unsigned short* __restrict__ Vt) {
  __shared__ __attribute__((aligned(16))) unsigned short T[64 * 72];
  const int t0 = blockIdx.x * 64, d0 = blockIdx.y * 64, h = blockIdx.z;
  const int tid = threadIdx.x;
#pragma unroll
  for (int i = 0; i < 2; ++i) {
    int c = tid + i * 256;
    int r = c >> 3, cc = c & 7;            // r: t-local row, cc: d chunk
    *(f32x4*)(T + r * 72 + cc * 8) =
        *(const f32x4*)(Vh + (size_t)(t0 + r) * E_DIM + h * DKD + d0 + cc * 8);
  }
  __syncthreads();
#pragma unroll
  for (int i = 0; i < 2; ++i) {
    int c = tid + i * 256;
    int r = c >> 3, cc = c & 7;            // r: d-local row, cc: t chunk
    unsigned short tmp[8] __attribute__((aligned(16)));
#pragma unroll
    for (int j = 0; j < 8; ++j) tmp[j] = T[(cc * 8 + j) * 72 + r];
    *(f32x4*)(Vt + (size_t)(h * DKD + d0 + r) * S_LEN + t0 + cc * 8) = *(const f32x4*)tmp;
  }
}

// ---------------- flash attention with mask + post-softmax group_prob ----------------
// grid (H, S/64); block 256 = 4 waves; wave w owns query rows w*16..w*16+16 of the tile.
__global__ __launch_bounds__(256) void attn_fwd(
    const unsigned short* __restrict__ Qh, const unsigned short* __restrict__ Kh,
    const unsigned short* __restrict__ Vt, const int* __restrict__ mask,
    const float* __restrict__ gp, unsigned short* __restrict__ Z) {
  __shared__ __attribute__((aligned(16))) unsigned short Qs[64 * 136];
  __shared__ __attribute__((aligned(16))) unsigned short Ks[64 * 136];
  __shared__ __attribute__((aligned(16))) unsigned short Vs[128 * 72];
  __shared__ __attribute__((aligned(16))) unsigned short Ps[4][16 * 72];
  const int h = blockIdx.x;
  const int q0 = blockIdx.y * 64;
  const int tid = threadIdx.x;
  const int wave = tid >> 6, lane = tid & 63;
  const int quad = lane >> 4, l15 = lane & 15;

  // stage Q tile (64 x 128), row pad 136 elems
#pragma unroll
  for (int i = 0; i < 4; ++i) {
    int c = tid + i * 256;
    int r = c >> 4, cc = c & 15;
    *(f32x4*)(Qs + r * 136 + cc * 8) =
        *(const f32x4*)(Qh + (size_t)(q0 + r) * E_DIM + h * DKD + cc * 8);
  }
  float m_i[4], l_i[4];
#pragma unroll
  for (int r = 0; r < 4; ++r) { m_i[r] = -1e30f; l_i[r] = 0.0f; }
  const f32x4 zero4 = {0.f, 0.f, 0.f, 0.f};
  f32x4 o[8];
#pragma unroll
  for (int d = 0; d < 8; ++d) o[d] = zero4;

  for (int t0 = 0; t0 < S_LEN; t0 += 64) {
    __syncthreads();
    // stage K tile (64 keys x 128)
#pragma unroll
    for (int i = 0; i < 4; ++i) {
      int c = tid + i * 256;
      int r = c >> 4, cc = c & 15;
      *(f32x4*)(Ks + r * 136 + cc * 8) =
          *(const f32x4*)(Kh + (size_t)(t0 + r) * E_DIM + h * DKD + cc * 8);
    }
    // stage V tile transposed: Vs[d][t], 128 x 64 (row pad 72)
#pragma unroll
    for (int i = 0; i < 4; ++i) {
      int c = tid + i * 256;
      int r = c >> 3, cc = c & 7;
      *(f32x4*)(Vs + r * 72 + cc * 8) =
          *(const f32x4*)(Vt + (size_t)(h * DKD + r) * S_LEN + t0 + cc * 8);
    }
    __syncthreads();

    // S = Q K^T (Q pre-scaled by 1/sqrt(DK))
    short8 aq[4];
#pragma unroll
    for (int kk = 0; kk < 4; ++kk)
      aq[kk] = *(const short8*)(Qs + (wave * 16 + l15) * 136 + kk * 32 + quad * 8);
    f32x4 sA[4];
#pragma unroll
    for (int nt = 0; nt < 4; ++nt) {
      sA[nt] = zero4;
#pragma unroll
      for (int kk = 0; kk < 4; ++kk) {
        short8 bK = *(const short8*)(Ks + (nt * 16 + l15) * 136 + kk * 32 + quad * 8);
        sA[nt] = __builtin_amdgcn_mfma_f32_16x16x32_bf16(aq[kk], bK, sA[nt], 0, 0, 0);
      }
    }

    // mask (exact -1e9 replacement, as reference)
    const int srow = q0 + wave * 16 + quad * 4;
    float p[4][4];
#pragma unroll
    for (int nt = 0; nt < 4; ++nt) {
      int tg = t0 + nt * 16 + l15;
#pragma unroll
      for (int r = 0; r < 4; ++r) {
        int mv = mask[(size_t)(srow + r) * S_LEN + tg];
        p[nt][r] = (mv != 0) ? sA[nt][r] : -1e9f;
      }
    }

    // online softmax per query row (rows live in 16-lane quad groups)
#pragma unroll
    for (int r = 0; r < 4; ++r) {
      float vm = fmaxf(fmaxf(p[0][r], p[1][r]), fmaxf(p[2][r], p[3][r]));
#pragma unroll
      for (int off = 1; off < 16; off <<= 1)
        vm = fmaxf(vm, __shfl_xor(vm, off, 64));
      float mnew = fmaxf(m_i[r], vm);
      float alpha = __expf(m_i[r] - mnew);
      m_i[r] = mnew;
      float ps = 0.0f;
#pragma unroll
      for (int nt = 0; nt < 4; ++nt) {
        float pv = __expf(p[nt][r] - mnew);
        p[nt][r] = pv;
        ps += pv;
      }
#pragma unroll
      for (int off = 1; off < 16; off <<= 1)
        ps += __shfl_xor(ps, off, 64);
      l_i[r] = l_i[r] * alpha + ps;       // l WITHOUT group_prob (post-softmax scale)
#pragma unroll
      for (int dt = 0; dt < 8; ++dt) o[dt][r] *= alpha;
    }

    // P = exp(s-m) * group_prob -> bf16 in per-wave LDS (C-layout -> A-layout)
#pragma unroll
    for (int nt = 0; nt < 4; ++nt) {
      int tg = t0 + nt * 16 + l15;
#pragma unroll
      for (int r = 0; r < 4; ++r) {
        float gv = gp[(size_t)(srow + r) * S_LEN + tg];
        Ps[wave][(quad * 4 + r) * 72 + nt * 16 + l15] = f32_to_bf16(p[nt][r] * gv);
      }
    }
    __syncthreads();

    // O += P V
    short8 ap0 = *(const short8*)(&Ps[wave][l15 * 72 + quad * 8]);
    short8 ap1 = *(const short8*)(&Ps[wave][l15 * 72 + 32 + quad * 8]);
#pragma unroll
    for (int dt = 0; dt < 8; ++dt) {
      short8 b0 = *(const short8*)(Vs + (dt * 16 + l15) * 72 + quad * 8);
      short8 b1 = *(const short8*)(Vs + (dt * 16 + l15) * 72 + 32 + quad * 8);
      o[dt] = __builtin_amdgcn_mfma_f32_16x16x32_bf16(ap0, b0, o[dt], 0, 0, 0);
      o[dt] = __builtin_amdgcn_mfma_f32_16x16x32_bf16(ap1, b1, o[dt], 0, 0, 0);
    }
  }

  // epilogue: divide by l, write bf16 Z[s, h*DK + d]
#pragma unroll
  for (int dt = 0; dt < 8; ++dt) {
#pragma unroll
    for (int r = 0; r < 4; ++r) {
      int gr = q0 + wave * 16 + quad * 4 + r;
      int gc = h * DKD + dt * 16 + l15;
      Z[(size_t)gr * E_DIM + gc] = f32_to_bf16(o[dt][r] / l_i[r]);
    }
  }
}

// ---------------- LayerNorm over last dim (1024), one block per row ----------------
__global__ __launch_bounds__(256) void ln_fwd(const float* __restrict__ Y,
                                              const float* __restrict__ g,
                                              const float* __restrict__ b,
                                              float* __restrict__ out) {
  const int row = blockIdx.x;
  const int tid = threadIdx.x;
  const float* y = Y + (size_t)row * E_DIM;
  f32x4 v = *(const f32x4*)(y + tid * 4);
  float s = v.x + v.y + v.z + v.w;
  float s2 = v.x * v.x + v.y * v.y + v.z * v.z + v.w * v.w;
#pragma unroll
  for (int off = 32; off > 0; off >>= 1) {
    s += __shfl_down(s, off, 64);
    s2 += __shfl_down(s2, off, 64);
  }
  __shared__ float red[8];
  __shared__ float mu_s, rs_s;
  const int wave = tid >> 6, lane = tid & 63;
  if (lane == 0) { red[wave] = s; red[4 + wave] = s2; }
  __syncthreads();
  if (tid == 0) {
    float ts = red[0] + red[1] + red[2] + red[3];
    float ts2 = red[4] + red[5] + red[6] + red[7];
    float mu = ts * (1.0f / E_DIM);
    float var = ts2 * (1.0f / E_DIM) - mu * mu;
    mu_s = mu;
    rs_s = rsqrtf(var + 1e-5f);
  }
  __syncthreads();
  const float mu = mu_s, rs = rs_s;
  f32x4 gg = *(const f32x4*)(g + tid * 4);
  f32x4 bb = *(const f32x4*)(b + tid * 4);
  f32x4 ov;
  ov.x = (v.x - mu) * rs * gg.x + bb.x;
  ov.y = (v.y - mu) * rs * gg.y + bb.y;
  ov.z = (v.z - mu) * rs * gg.z + bb.z;
  ov.w = (v.w - mu) * rs * gg.w + bb.w;
  *(f32x4*)(out + (size_t)row * E_DIM + tid * 4) = ov;
}

extern "C" void kernel_launch(void* const* d_in, const int* in_sizes, int n_in,
                              void* d_out, int out_size, void* d_ws, size_t ws_size,
                              hipStream_t stream) {
  const float* q   = (const float*)d_in[0];
  const float* k   = (const float*)d_in[1];
  const float* v   = (const float*)d_in[2];
  const int*  mask = (const int*)d_in[3];
  const float* gp  = (const float*)d_in[4];
  const float* Wq  = (const float*)d_in[5];
  const float* bq  = (const float*)d_in[6];
  const float* Wk  = (const float*)d_in[7];
  const float* bk  = (const float*)d_in[8];
  const float* Wv  = (const float*)d_in[9];
  const float* bv  = (const float*)d_in[10];
  const float* Wo  = (const float*)d_in[11];
  const float* bo  = (const float*)d_in[12];
  const float* lng = (const float*)d_in[13];
  const float* lnb = (const float*)d_in[14];

  char* ws = (char*)d_ws;
  const size_t MB = 1024 * 1024;
  // workspace layout (88 MB total)
  unsigned short* WB = (unsigned short*)(ws + 0);        // Wq,Wk,Wv,Wo bf16 (8 MB)
  unsigned short* QB = (unsigned short*)(ws + 8 * MB);   // q bf16
  unsigned short* KB = (unsigned short*)(ws + 16 * MB);
  unsigned short* VB = (unsigned short*)(ws + 24 * MB);
  unsigned short* QH = (unsigned short*)(ws + 32 * MB);  // projected, Q pre-scaled
  unsigned short* KH = (unsigned short*)(ws + 40 * MB);
  unsigned short* VH = (unsigned short*)(ws + 48 * MB);
  unsigned short* VT = (unsigned short*)(ws + 56 * MB);  // V transposed [H][DK][S]
  unsigned short* ZB = (unsigned short*)(ws + 64 * MB);  // attention output bf16
  float* YF = (float*)(ws + 72 * MB);                    // pre-LN fp32 (16 MB)

  const int nQKV = S_LEN * E_DIM;  // 4 M
  const int nW = E_DIM * E_DIM;    // 1 M
  cvt_f32_bf16<<<nQKV / 1024, 256, 0, stream>>>(q, QB, nQKV);
  cvt_f32_bf16<<<nQKV / 1024, 256, 0, stream>>>(k, KB, nQKV);
  cvt_f32_bf16<<<nQKV / 1024, 256, 0, stream>>>(v, VB, nQKV);
  cvt_f32_bf16<<<nW / 1024, 256, 0, stream>>>(Wq, WB + 0 * (size_t)nW, nW);
  cvt_f32_bf16<<<nW / 1024, 256, 0, stream>>>(Wk, WB + 1 * (size_t)nW, nW);
  cvt_f32_bf16<<<nW / 1024, 256, 0, stream>>>(Wv, WB + 2 * (size_t)nW, nW);
  cvt_f32_bf16<<<nW / 1024, 256, 0, stream>>>(Wo, WB + 3 * (size_t)nW, nW);

  proj_qkv<<<dim3(8, 32, 3), 256, 0, stream>>>(QB, KB, VB, WB, bq, bk, bv,
                                               QH, KH, VH, 0.08838834764831845f);
  transpose_v<<<dim3(64, 2, 8), 256, 0, stream>>>(VH, VT);
  attn_fwd<<<dim3(8, 64), 256, 0, stream>>>(QH, KH, VT, mask, gp, ZB);
  out_proj<<<dim3(8, 32), 256, 0, stream>>>(ZB, WB + 3 * (size_t)nW, bo, q, YF);
  ln_fwd<<<S_LEN, 256, 0, stream>>>(YF, lng, lnb, (float*)d_out);
}